// Round 4
// baseline (161.263 us; speedup 1.0000x reference)
//
#include <hip/hip_runtime.h>
#include <hip/hip_cooperative_groups.h>
#include <stdint.h>

namespace cg = cooperative_groups;

// ---- problem constants ----
#define S_LEN   2048
#define HIDDEN  768
#define NHEADS  12
#define QKV_LD  2304   // fused q|k|v row stride (elements)
#define NW      589824 // 768*768

typedef __attribute__((ext_vector_type(8))) short short8;
typedef __attribute__((ext_vector_type(4))) float f32x4;

typedef const __attribute__((address_space(1))) void* gas_ptr;
typedef __attribute__((address_space(3))) void* las_ptr;

__device__ __forceinline__ short f2b(float f) {
    union { float f; uint32_t u; } v; v.f = f;
    uint32_t u = v.u;
    uint32_t r = (u + 0x7FFFu + ((u >> 16) & 1u)) >> 16;
    return (short)r;
}

// ---------------- phase A: f32 -> bf16 convert, chunk = 1024 elems ----------------
// chunks [0,1536): X. chunks [1536, 1536+4*576): Wq,Wk,Wv,Wo.
__device__ __forceinline__ void convert_chunk(int b,
    const float* __restrict__ X, const float* __restrict__ Wq,
    const float* __restrict__ Wk, const float* __restrict__ Wv,
    const float* __restrict__ Wo,
    short* __restrict__ Xb, short* __restrict__ Wqkvb, short* __restrict__ Wob) {
    const float* src; short* dst; int i;
    if (b < 1536) {
        src = X; dst = Xb; i = b * 1024 + threadIdx.x * 4;
    } else {
        int wb = (b - 1536) / 576, lb = (b - 1536) % 576;
        src = wb == 0 ? Wq : wb == 1 ? Wk : wb == 2 ? Wv : Wo;
        dst = wb < 3 ? Wqkvb + wb * NW : Wob;
        i = lb * 1024 + threadIdx.x * 4;
    }
    float4 v = *(const float4*)(src + i);
    *(short4*)(dst + i) = make_short4(f2b(v.x), f2b(v.y), f2b(v.z), f2b(v.w));
}

// ---------------- GEMM tile: C[64 x BN] += A[64xK] . B[BN x K]^T, K=768 ----------------
// 4 waves (2x2), mfma_f32_16x16x32_bf16, XOR-swizzled LDS, double-buffered.
// smem layout: sA[2][64*64]sh @0 (16KB), sB[2][BN*64]sh @16KB (32KB for BN=128).
template<int BN, int OUT_BF16>
__device__ __forceinline__ void gemm_tile(const short* __restrict__ A,
    const short* __restrict__ B, void* __restrict__ Cv,
    int bm, int bn, int ldc, char* smem) {
    const int tid = threadIdx.x, lane = tid & 63, w = tid >> 6;
    const int wr = w >> 1, wc = w & 1;
    constexpr int NF = BN / 32;           // col fragments per wave
    f32x4 acc[2][NF] = {};
    char* sB = smem + 16384;

    auto stage = [&](int buf, int k0) {
        #pragma unroll
        for (int c = 0; c < 2; ++c) {
            int r = w * 16 + c * 8 + (lane >> 3);
            int scb = ((lane & 7) * 16) ^ ((r & 7) << 4);
            const char* gp = (const char*)(A + (size_t)(bm * 64 + r) * 768 + k0) + scb;
            __builtin_amdgcn_global_load_lds((gas_ptr)gp,
                (las_ptr)(smem + buf * 8192 + w * 2048 + c * 1024), 16, 0, 0);
        }
        #pragma unroll
        for (int c = 0; c < NF; ++c) {
            int r = w * (BN / 4) + c * 8 + (lane >> 3);
            int scb = ((lane & 7) * 16) ^ ((r & 7) << 4);
            const char* gp = (const char*)(B + (size_t)(bn * BN + r) * 768 + k0) + scb;
            __builtin_amdgcn_global_load_lds((gas_ptr)gp,
                (las_ptr)(sB + buf * (BN * 128) + w * (BN * 32) + c * 1024), 16, 0, 0);
        }
    };

    stage(0, 0);
    __syncthreads();
    int cur = 0;
    for (int t = 0; t < 12; ++t) {
        if (t < 11) stage(cur ^ 1, (t + 1) * 64);
        #pragma unroll
        for (int kh = 0; kh < 2; ++kh) {
            const int kb = kh * 64 + ((lane >> 4) << 4);
            short8 av[2], bv[NF];
            #pragma unroll
            for (int mi = 0; mi < 2; ++mi) {
                int row = wr * 32 + mi * 16 + (lane & 15);
                av[mi] = *(const short8*)(smem + cur * 8192 + row * 128 + (kb ^ ((row & 7) << 4)));
            }
            #pragma unroll
            for (int ni = 0; ni < NF; ++ni) {
                int row = wc * (BN / 2) + ni * 16 + (lane & 15);
                bv[ni] = *(const short8*)(sB + cur * (BN * 128) + row * 128 + (kb ^ ((row & 7) << 4)));
            }
            #pragma unroll
            for (int mi = 0; mi < 2; ++mi)
                #pragma unroll
                for (int ni = 0; ni < NF; ++ni)
                    acc[mi][ni] = __builtin_amdgcn_mfma_f32_16x16x32_bf16(
                        av[mi], bv[ni], acc[mi][ni], 0, 0, 0);
        }
        __syncthreads();
        cur ^= 1;
    }

    #pragma unroll
    for (int mi = 0; mi < 2; ++mi)
        #pragma unroll
        for (int ni = 0; ni < NF; ++ni)
            #pragma unroll
            for (int r = 0; r < 4; ++r) {
                int grow = bm * 64 + wr * 32 + mi * 16 + ((lane >> 4) << 2) + r;
                int gcol = bn * BN + wc * (BN / 2) + ni * 16 + (lane & 15);
                if (OUT_BF16)
                    ((short*)Cv)[(size_t)grow * ldc + gcol] = f2b(acc[mi][ni][r]);
                else
                    ((float*)Cv)[(size_t)grow * ldc + gcol] = acc[mi][ni][r];
            }
}

// ---------------- MFMA sliding-window attention tile ----------------
// task = (64-query tile, head). K/V staged for rows [s0-64, s0+63].
// smem: sK 16KB @0, sVt 16KB @16K, sP 4x4KB @32K.
__device__ __forceinline__ void attn_tile(const short* __restrict__ QKV,
    short* __restrict__ O, int task, char* smem) {
    const int h = task % NHEADS;
    const int s0 = (task / NHEADS) * 64;
    const int tid = threadIdx.x, lane = tid & 63, w = tid >> 6;
    char* sK  = smem;
    char* sVt = smem + 16384;
    char* sPw = smem + 32768 + w * 4096;

    #pragma unroll
    for (int c = 0; c < 4; ++c) {
        int r = (w * 4 + c) * 8 + (lane >> 3);
        int gr = s0 - 64 + r; if (gr < 0) gr = 0;
        int scb = ((lane & 7) * 16) ^ ((r & 7) << 4);
        const char* gp = (const char*)(QKV + (size_t)gr * QKV_LD + 768 + h * 64) + scb;
        __builtin_amdgcn_global_load_lds((gas_ptr)gp,
            (las_ptr)(sK + (w * 4 + c) * 1024), 16, 0, 0);
    }
    {   // V transposed: thread = (4 keys, 8 dims) -> 8x ds_write_b64
        const int d0 = (tid & 7) * 8;
        const int kbase = (tid >> 3) * 4;
        short8 v[4];
        #pragma unroll
        for (int i = 0; i < 4; ++i) {
            int gr = s0 - 64 + kbase + i; if (gr < 0) gr = 0;
            v[i] = *(const short8*)(QKV + (size_t)gr * QKV_LD + 1536 + h * 64 + d0);
        }
        #pragma unroll
        for (int j = 0; j < 8; ++j) {
            int row = d0 + j;
            int b = row * 256 + ((kbase * 2) ^ ((row & 7) << 4));
            *(short4*)(sVt + b) = make_short4(v[0][j], v[1][j], v[2][j], v[3][j]);
        }
    }
    const int qrow = w * 16 + (lane & 15);
    short8 qf[2];
    #pragma unroll
    for (int kk = 0; kk < 2; ++kk)
        qf[kk] = *(const short8*)(QKV + (size_t)(s0 + qrow) * QKV_LD + h * 64
                                  + kk * 32 + ((lane >> 4) << 3));
    __syncthreads();

    f32x4 s_acc[8];
    #pragma unroll
    for (int ct = 0; ct < 8; ++ct) {
        s_acc[ct] = (f32x4){0.f, 0.f, 0.f, 0.f};
        int krow = ct * 16 + (lane & 15);
        #pragma unroll
        for (int kk = 0; kk < 2; ++kk) {
            int cb = kk * 64 + ((lane >> 4) << 4);
            short8 kf = *(const short8*)(sK + krow * 128 + (cb ^ ((krow & 7) << 4)));
            s_acc[ct] = __builtin_amdgcn_mfma_f32_16x16x32_bf16(qf[kk], kf, s_acc[ct], 0, 0, 0);
        }
    }

    const int kcol = lane & 15;
    const int qb = w * 16 + ((lane >> 4) << 2);
    float p[8][4];
    #pragma unroll
    for (int r = 0; r < 4; ++r) {
        int q = qb + r;
        float m = -1e30f;
        #pragma unroll
        for (int ct = 0; ct < 8; ++ct) {
            int kt = ct * 16 + kcol;
            bool valid = (kt > q) && (kt <= q + 64) && (s0 + kt >= 64);
            float sc = valid ? s_acc[ct][r] * 0.125f : -1e30f;
            p[ct][r] = sc;
            m = fmaxf(m, sc);
        }
        #pragma unroll
        for (int off = 1; off < 16; off <<= 1) m = fmaxf(m, __shfl_xor(m, off));
        float sm = 0.f;
        #pragma unroll
        for (int ct = 0; ct < 8; ++ct) {
            float e = __expf(p[ct][r] - m);
            p[ct][r] = e;
            sm += e;
        }
        #pragma unroll
        for (int off = 1; off < 16; off <<= 1) sm += __shfl_xor(sm, off);
        float inv = 1.f / sm;
        #pragma unroll
        for (int ct = 0; ct < 8; ++ct) p[ct][r] *= inv;
    }

    #pragma unroll
    for (int ct = 0; ct < 8; ++ct)
        #pragma unroll
        for (int r = 0; r < 4; ++r) {
            int row = ((lane >> 4) << 2) + r;
            int b = row * 256 + (((ct * 16 + kcol) * 2) ^ ((row & 7) << 4));
            *(short*)(sPw + b) = f2b(p[ct][r]);
        }

    short8 pf[4];
    #pragma unroll
    for (int kk = 0; kk < 4; ++kk) {
        int row = lane & 15;
        int cb = kk * 64 + ((lane >> 4) << 4);
        pf[kk] = *(const short8*)(sPw + row * 256 + (cb ^ ((row & 7) << 4)));
    }
    f32x4 o_acc[4];
    #pragma unroll
    for (int nt = 0; nt < 4; ++nt) {
        o_acc[nt] = (f32x4){0.f, 0.f, 0.f, 0.f};
        #pragma unroll
        for (int kk = 0; kk < 4; ++kk) {
            int vrow = nt * 16 + (lane & 15);
            int cb = kk * 64 + ((lane >> 4) << 4);
            short8 vf = *(const short8*)(sVt + vrow * 256 + (cb ^ ((vrow & 7) << 4)));
            o_acc[nt] = __builtin_amdgcn_mfma_f32_16x16x32_bf16(pf[kk], vf, o_acc[nt], 0, 0, 0);
        }
    }

    #pragma unroll
    for (int nt = 0; nt < 4; ++nt)
        #pragma unroll
        for (int r = 0; r < 4; ++r) {
            int q = s0 + qb + r;
            int dcol = h * 64 + nt * 16 + (lane & 15);
            O[(size_t)q * HIDDEN + dcol] = f2b(o_acc[nt][r]);
        }
    __syncthreads();   // LDS reuse guard
}

// ---------------- fused persistent cooperative kernel ----------------
__global__ __launch_bounds__(256, 2)
void fused_all(const float* __restrict__ X,
               const float* __restrict__ Wq, const float* __restrict__ Wk,
               const float* __restrict__ Wv, const float* __restrict__ Wo,
               float* __restrict__ out, char* __restrict__ ws) {
    __shared__ __align__(16) char smem[49152];
    short* Xb    = (short*)ws;
    short* Wqkvb = (short*)(ws + 3145728);
    short* Wob   = (short*)(ws + 6684672);
    short* QKVb  = (short*)(ws + 7864320);
    short* Attnb = (short*)(ws + 17301504);
    cg::grid_group grid = cg::this_grid();
    const int gs = gridDim.x;

    // A: converts (3840 chunks)
    for (int b = blockIdx.x; b < 3840; b += gs)
        convert_chunk(b, X, Wq, Wk, Wv, Wo, Xb, Wqkvb, Wob);
    grid.sync();

    // B: QKV GEMM, 32x18 tiles of 64x128 -> bf16
    for (int t = blockIdx.x; t < 32 * 18; t += gs)
        gemm_tile<128, 1>(Xb, Wqkvb, QKVb, t / 18, t % 18, QKV_LD, smem);
    grid.sync();

    // C: attention, 384 tiles
    for (int t = blockIdx.x; t < 384; t += gs)
        attn_tile(QKVb, Attnb, t, smem);
    grid.sync();

    // D: out GEMM, 32x12 tiles of 64x64 -> f32
    for (int t = blockIdx.x; t < 32 * 12; t += gs)
        gemm_tile<64, 0>(Attnb, Wob, out, t / 12, t % 12, HIDDEN, smem);
}

// ---------------- non-cooperative fallback wrappers ----------------
__global__ __launch_bounds__(256)
void k_convert(const float* __restrict__ X, const float* __restrict__ Wq,
               const float* __restrict__ Wk, const float* __restrict__ Wv,
               const float* __restrict__ Wo, short* __restrict__ Xb,
               short* __restrict__ Wqkvb, short* __restrict__ Wob) {
    convert_chunk(blockIdx.x, X, Wq, Wk, Wv, Wo, Xb, Wqkvb, Wob);
}
__global__ __launch_bounds__(256)
void k_gemm_qkv(const short* __restrict__ A, const short* __restrict__ B,
                short* __restrict__ C) {
    __shared__ __align__(16) char smem[49152];
    gemm_tile<128, 1>(A, B, C, blockIdx.x / 18, blockIdx.x % 18, QKV_LD, smem);
}
__global__ __launch_bounds__(256)
void k_attn(const short* __restrict__ QKV, short* __restrict__ O) {
    __shared__ __align__(16) char smem[49152];
    attn_tile(QKV, O, blockIdx.x, smem);
}
__global__ __launch_bounds__(256)
void k_gemm_out(const short* __restrict__ A, const short* __restrict__ B,
                float* __restrict__ C) {
    __shared__ __align__(16) char smem[49152];
    gemm_tile<64, 0>(A, B, C, blockIdx.x / 12, blockIdx.x % 12, HIDDEN, smem);
}

// ---------------- launcher ----------------
extern "C" void kernel_launch(void* const* d_in, const int* in_sizes, int n_in,
                              void* d_out, int out_size, void* d_ws, size_t ws_size,
                              hipStream_t stream) {
    const float* X  = (const float*)d_in[0];
    const float* Wq = (const float*)d_in[1];
    const float* Wk = (const float*)d_in[2];
    const float* Wv = (const float*)d_in[3];
    const float* Wo = (const float*)d_in[4];
    float* out = (float*)d_out;
    char* ws = (char*)d_ws;

    int maxb = 0;
    hipError_t oe = hipOccupancyMaxActiveBlocksPerMultiprocessor(&maxb, fused_all, 256, 0);
    int grid = (oe == hipSuccess) ? maxb * 256 : 0;
    if (grid > 512) grid = 512;

    if (grid >= 64) {
        void* args[7] = {(void*)&X, (void*)&Wq, (void*)&Wk, (void*)&Wv,
                         (void*)&Wo, (void*)&out, (void*)&ws};
        hipError_t e = hipLaunchCooperativeKernel((const void*)fused_all,
                           dim3(grid), dim3(256), args, 0, stream);
        if (e == hipSuccess) return;
    }

    // fallback: separate launches
    short* Xb    = (short*)ws;
    short* Wqkvb = (short*)(ws + 3145728);
    short* Wob   = (short*)(ws + 6684672);
    short* QKVb  = (short*)(ws + 7864320);
    short* Attnb = (short*)(ws + 17301504);
    k_convert<<<3840, 256, 0, stream>>>(X, Wq, Wk, Wv, Wo, Xb, Wqkvb, Wob);
    k_gemm_qkv<<<32 * 18, 256, 0, stream>>>(Xb, Wqkvb, QKVb);
    k_attn<<<384, 256, 0, stream>>>(QKVb, Attnb);
    k_gemm_out<<<32 * 12, 256, 0, stream>>>(Attnb, Wob, out);
}

// Round 5
// 91.399 us; speedup vs baseline: 1.7644x; 1.7644x over previous
//
#include <hip/hip_runtime.h>
#include <stdint.h>

// ---- problem constants ----
#define S_LEN   2048
#define HIDDEN  768
#define NHEADS  12
#define QKV_LD  2304   // fused q|k|v row stride (elements)

typedef __attribute__((ext_vector_type(8))) short short8;
typedef __attribute__((ext_vector_type(4))) float f32x4;

typedef const __attribute__((address_space(1))) void* gas_ptr;
typedef __attribute__((address_space(3))) void* las_ptr;

__device__ __forceinline__ short f2b(float f) {
    union { float f; uint32_t u; } v; v.f = f;
    uint32_t u = v.u;
    uint32_t r = (u + 0x7FFFu + ((u >> 16) & 1u)) >> 16;
    return (short)r;
}

__device__ __forceinline__ short8 pack8(float4 a, float4 b) {
    short8 r;
    r[0] = f2b(a.x); r[1] = f2b(a.y); r[2] = f2b(a.z); r[3] = f2b(a.w);
    r[4] = f2b(b.x); r[5] = f2b(b.y); r[6] = f2b(b.z); r[7] = f2b(b.w);
    return r;
}

// ================= Kernel 1: QKV = X @ [Wq;Wk;Wv]^T (f32 in, bf16 out) =======
// M=2048, N=2304, K=768. Tile 128x128, BK=64, 4 waves.
// f32->bf16 fused into reg-staging; T14 async-split (loads for t+1 in flight
// during compute of t); one barrier per K-step; XOR-swizzled LDS.
__global__ __launch_bounds__(256)
void gemm_qkv(const float* __restrict__ X, const float* __restrict__ Wq,
              const float* __restrict__ Wk, const float* __restrict__ Wv,
              short* __restrict__ C) {
    __shared__ short sA[2][128 * 64];
    __shared__ short sB[2][128 * 64];

    const int bid = blockIdx.x;                 // 288 = 8*36
    const int sw = (bid & 7) * 36 + (bid >> 3); // XCD-chunked, bijective
    const int bm = sw / 18, bn = sw % 18;
    const float* Bm = (bn < 6) ? Wq : (bn < 12) ? Wk : Wv;
    const int bro = (bn % 6) * 128;

    const int tid = threadIdx.x, lane = tid & 63, w = tid >> 6;
    const int wr = w >> 1, wc = w & 1;
    const int srow = tid >> 1, shalf = tid & 1;   // staging: row 0..127, col-half

    f32x4 acc[4][4] = {};
    float4 ra[8], rb[8];

    auto load = [&](int k0) {
        const float* ap = X + (size_t)(bm * 128 + srow) * 768 + k0 + shalf * 32;
        #pragma unroll
        for (int j = 0; j < 8; ++j) ra[j] = *(const float4*)(ap + j * 4);
        const float* bp = Bm + (size_t)(bro + srow) * 768 + k0 + shalf * 32;
        #pragma unroll
        for (int j = 0; j < 8; ++j) rb[j] = *(const float4*)(bp + j * 4);
    };
    auto store_lds = [&](int buf) {
        #pragma unroll
        for (int i = 0; i < 4; ++i) {
            int byte = shalf * 64 + i * 16;
            int addr = srow * 128 + (byte ^ ((srow & 7) << 4));
            *(short8*)((char*)&sA[buf][0] + addr) = pack8(ra[2 * i], ra[2 * i + 1]);
            *(short8*)((char*)&sB[buf][0] + addr) = pack8(rb[2 * i], rb[2 * i + 1]);
        }
    };

    load(0);
    for (int t = 0; t < 12; ++t) {
        const int cur = t & 1;
        store_lds(cur);            // implicit vmcnt wait on this tile's loads
        __syncthreads();
        if (t < 11) load((t + 1) * 64);   // in flight during compute below

        #pragma unroll
        for (int kh = 0; kh < 2; ++kh) {
            const int kb = kh * 64 + ((lane >> 4) << 4);
            short8 av[4], bv[4];
            #pragma unroll
            for (int mi = 0; mi < 4; ++mi) {
                int row = wr * 64 + mi * 16 + (lane & 15);
                av[mi] = *(const short8*)((const char*)&sA[cur][0] + row * 128 + (kb ^ ((row & 7) << 4)));
            }
            #pragma unroll
            for (int ni = 0; ni < 4; ++ni) {
                int row = wc * 64 + ni * 16 + (lane & 15);
                bv[ni] = *(const short8*)((const char*)&sB[cur][0] + row * 128 + (kb ^ ((row & 7) << 4)));
            }
            #pragma unroll
            for (int mi = 0; mi < 4; ++mi)
                #pragma unroll
                for (int ni = 0; ni < 4; ++ni)
                    acc[mi][ni] = __builtin_amdgcn_mfma_f32_16x16x32_bf16(
                        av[mi], bv[ni], acc[mi][ni], 0, 0, 0);
        }
    }

    const int crow0 = bm * 128 + wr * 64;
    const int ccol0 = bn * 128 + wc * 64;
    #pragma unroll
    for (int mi = 0; mi < 4; ++mi)
        #pragma unroll
        for (int ni = 0; ni < 4; ++ni)
            #pragma unroll
            for (int r = 0; r < 4; ++r) {
                int grow = crow0 + mi * 16 + ((lane >> 4) << 2) + r;
                int gcol = ccol0 + ni * 16 + (lane & 15);
                C[(size_t)grow * QKV_LD + gcol] = f2b(acc[mi][ni][r]);
            }
}

// ================= Kernel 2: MFMA sliding-window attention ===================
// QKV: [S][2304] bf16. O: [S][768] bf16. Block = (head, 64-query tile).
__global__ __launch_bounds__(256)
void attn_mfma(const short* __restrict__ QKV, short* __restrict__ O) {
    __shared__ short sK[128 * 64];       // [kt][d]  swz, 16KB
    __shared__ short sVt[64 * 128];      // [d][kt]  swz, 16KB
    __shared__ short sP[4][16 * 128];    // per-wave [q][kt] swz, 16KB

    const int bid = blockIdx.x;                 // 384 = 8*48
    const int task = (bid & 7) * 48 + (bid >> 3);
    const int h = task % NHEADS;
    const int s0 = (task / NHEADS) * 64;
    const int tid = threadIdx.x, lane = tid & 63, w = tid >> 6;

    #pragma unroll
    for (int c = 0; c < 4; ++c) {
        int r = (w * 4 + c) * 8 + (lane >> 3);
        int gr = s0 - 64 + r; if (gr < 0) gr = 0;
        int scb = ((lane & 7) * 16) ^ ((r & 7) << 4);
        const char* gp = (const char*)(QKV + (size_t)gr * QKV_LD + 768 + h * 64) + scb;
        __builtin_amdgcn_global_load_lds((gas_ptr)gp,
            (las_ptr)((char*)sK + (w * 4 + c) * 1024), 16, 0, 0);
    }
    {   // V transposed: thread = (4 keys, 8 dims) -> 8x ds_write_b64
        const int d0 = (tid & 7) * 8;
        const int kbase = (tid >> 3) * 4;
        short8 v[4];
        #pragma unroll
        for (int i = 0; i < 4; ++i) {
            int gr = s0 - 64 + kbase + i; if (gr < 0) gr = 0;
            v[i] = *(const short8*)(QKV + (size_t)gr * QKV_LD + 1536 + h * 64 + d0);
        }
        #pragma unroll
        for (int j = 0; j < 8; ++j) {
            int row = d0 + j;
            int b = row * 256 + ((kbase * 2) ^ ((row & 7) << 4));
            *(short4*)((char*)sVt + b) = make_short4(v[0][j], v[1][j], v[2][j], v[3][j]);
        }
    }
    const int qrow = w * 16 + (lane & 15);
    short8 qf[2];
    #pragma unroll
    for (int kk = 0; kk < 2; ++kk)
        qf[kk] = *(const short8*)(QKV + (size_t)(s0 + qrow) * QKV_LD + h * 64
                                  + kk * 32 + ((lane >> 4) << 3));
    __syncthreads();

    f32x4 s_acc[8];
    #pragma unroll
    for (int ct = 0; ct < 8; ++ct) {
        s_acc[ct] = (f32x4){0.f, 0.f, 0.f, 0.f};
        int krow = ct * 16 + (lane & 15);
        #pragma unroll
        for (int kk = 0; kk < 2; ++kk) {
            int cb = kk * 64 + ((lane >> 4) << 4);
            short8 kf = *(const short8*)((const char*)sK + krow * 128 + (cb ^ ((krow & 7) << 4)));
            s_acc[ct] = __builtin_amdgcn_mfma_f32_16x16x32_bf16(qf[kk], kf, s_acc[ct], 0, 0, 0);
        }
    }

    const int kcol = lane & 15;
    const int qb = w * 16 + ((lane >> 4) << 2);
    float p[8][4];
    #pragma unroll
    for (int r = 0; r < 4; ++r) {
        int q = qb + r;
        float m = -1e30f;
        #pragma unroll
        for (int ct = 0; ct < 8; ++ct) {
            int kt = ct * 16 + kcol;
            bool valid = (kt > q) && (kt <= q + 64) && (s0 + kt >= 64);
            float sc = valid ? s_acc[ct][r] * 0.125f : -1e30f;
            p[ct][r] = sc;
            m = fmaxf(m, sc);
        }
        #pragma unroll
        for (int off = 1; off < 16; off <<= 1) m = fmaxf(m, __shfl_xor(m, off));
        float sm = 0.f;
        #pragma unroll
        for (int ct = 0; ct < 8; ++ct) {
            float e = __expf(p[ct][r] - m);
            p[ct][r] = e;
            sm += e;
        }
        #pragma unroll
        for (int off = 1; off < 16; off <<= 1) sm += __shfl_xor(sm, off);
        float inv = 1.f / sm;
        #pragma unroll
        for (int ct = 0; ct < 8; ++ct) p[ct][r] *= inv;
    }

    #pragma unroll
    for (int ct = 0; ct < 8; ++ct)
        #pragma unroll
        for (int r = 0; r < 4; ++r) {
            int row = ((lane >> 4) << 2) + r;
            int b = row * 256 + (((ct * 16 + kcol) * 2) ^ ((row & 7) << 4));
            *(short*)((char*)&sP[w][0] + b) = f2b(p[ct][r]);
        }

    short8 pf[4];
    #pragma unroll
    for (int kk = 0; kk < 4; ++kk) {
        int row = lane & 15;
        int cb = kk * 64 + ((lane >> 4) << 4);
        pf[kk] = *(const short8*)((const char*)&sP[w][0] + row * 256 + (cb ^ ((row & 7) << 4)));
    }
    f32x4 o_acc[4];
    #pragma unroll
    for (int nt = 0; nt < 4; ++nt) {
        o_acc[nt] = (f32x4){0.f, 0.f, 0.f, 0.f};
        #pragma unroll
        for (int kk = 0; kk < 4; ++kk) {
            int vrow = nt * 16 + (lane & 15);
            int cb = kk * 64 + ((lane >> 4) << 4);
            short8 vf = *(const short8*)((const char*)sVt + vrow * 256 + (cb ^ ((vrow & 7) << 4)));
            o_acc[nt] = __builtin_amdgcn_mfma_f32_16x16x32_bf16(pf[kk], vf, o_acc[nt], 0, 0, 0);
        }
    }

    #pragma unroll
    for (int nt = 0; nt < 4; ++nt)
        #pragma unroll
        for (int r = 0; r < 4; ++r) {
            int q = s0 + qb + r;
            int dcol = h * 64 + nt * 16 + (lane & 15);
            O[(size_t)q * HIDDEN + dcol] = f2b(o_acc[nt][r]);
        }
}

// ================= Kernel 3: out = Attn @ Wo^T (A bf16, Wo f32, C f32) =======
// M=2048, N=768, K=768. Tile 64x128 -> 192 blocks. A via global_load_lds,
// B (Wo) reg-staged with fused convert. One barrier per K-step.
__global__ __launch_bounds__(256)
void gemm_out(const short* __restrict__ A, const float* __restrict__ Wo,
              float* __restrict__ C) {
    __shared__ short sA[2][64 * 64];
    __shared__ short sB[2][128 * 64];

    const int bid = blockIdx.x;                 // 192 = 8*24
    const int sw = (bid & 7) * 24 + (bid >> 3);
    const int bm = sw / 6, bn = sw % 6;

    const int tid = threadIdx.x, lane = tid & 63, w = tid >> 6;
    const int wr = w >> 1, wc = w & 1;
    const int srow = tid >> 1, shalf = tid & 1;

    f32x4 acc[2][4] = {};
    float4 rb[8];

    auto stageA = [&](int buf, int k0) {
        #pragma unroll
        for (int c = 0; c < 2; ++c) {
            int r = w * 16 + c * 8 + (lane >> 3);
            int scb = ((lane & 7) * 16) ^ ((r & 7) << 4);
            const char* gp = (const char*)(A + (size_t)(bm * 64 + r) * 768 + k0) + scb;
            __builtin_amdgcn_global_load_lds((gas_ptr)gp,
                (las_ptr)((char*)&sA[buf][0] + w * 2048 + c * 1024), 16, 0, 0);
        }
    };
    auto loadB = [&](int k0) {
        const float* bp = Wo + (size_t)(bn * 128 + srow) * 768 + k0 + shalf * 32;
        #pragma unroll
        for (int j = 0; j < 8; ++j) rb[j] = *(const float4*)(bp + j * 4);
    };
    auto storeB = [&](int buf) {
        #pragma unroll
        for (int i = 0; i < 4; ++i) {
            int byte = shalf * 64 + i * 16;
            int addr = srow * 128 + (byte ^ ((srow & 7) << 4));
            *(short8*)((char*)&sB[buf][0] + addr) = pack8(rb[2 * i], rb[2 * i + 1]);
        }
    };

    stageA(0, 0);
    loadB(0);
    for (int t = 0; t < 12; ++t) {
        const int cur = t & 1;
        storeB(cur);               // vmcnt wait covers this tile's A stage too
        __syncthreads();
        if (t < 11) { stageA(cur ^ 1, (t + 1) * 64); loadB((t + 1) * 64); }

        #pragma unroll
        for (int kh = 0; kh < 2; ++kh) {
            const int kb = kh * 64 + ((lane >> 4) << 4);
            short8 av[2], bv[4];
            #pragma unroll
            for (int mi = 0; mi < 2; ++mi) {
                int row = wr * 32 + mi * 16 + (lane & 15);
                av[mi] = *(const short8*)((const char*)&sA[cur][0] + row * 128 + (kb ^ ((row & 7) << 4)));
            }
            #pragma unroll
            for (int ni = 0; ni < 4; ++ni) {
                int row = wc * 64 + ni * 16 + (lane & 15);
                bv[ni] = *(const short8*)((const char*)&sB[cur][0] + row * 128 + (kb ^ ((row & 7) << 4)));
            }
            #pragma unroll
            for (int mi = 0; mi < 2; ++mi)
                #pragma unroll
                for (int ni = 0; ni < 4; ++ni)
                    acc[mi][ni] = __builtin_amdgcn_mfma_f32_16x16x32_bf16(
                        av[mi], bv[ni], acc[mi][ni], 0, 0, 0);
        }
    }

    const int crow0 = bm * 64 + wr * 32;
    const int ccol0 = bn * 128 + wc * 64;
    #pragma unroll
    for (int mi = 0; mi < 2; ++mi)
        #pragma unroll
        for (int ni = 0; ni < 4; ++ni)
            #pragma unroll
            for (int r = 0; r < 4; ++r) {
                int grow = crow0 + mi * 16 + ((lane >> 4) << 2) + r;
                int gcol = ccol0 + ni * 16 + (lane & 15);
                C[(size_t)grow * HIDDEN + gcol] = acc[mi][ni][r];
            }
}

// ---------------- launcher ----------------
extern "C" void kernel_launch(void* const* d_in, const int* in_sizes, int n_in,
                              void* d_out, int out_size, void* d_ws, size_t ws_size,
                              hipStream_t stream) {
    const float* X  = (const float*)d_in[0];
    const float* Wq = (const float*)d_in[1];
    const float* Wk = (const float*)d_in[2];
    const float* Wv = (const float*)d_in[3];
    const float* Wo = (const float*)d_in[4];
    float* out = (float*)d_out;

    char* ws = (char*)d_ws;
    short* QKVb  = (short*)ws;                  // 2048*2304 bf16 (9,437,184 B)
    short* Attnb = (short*)(ws + 9437184);      // 2048*768  bf16 (3,145,728 B)

    gemm_qkv<<<288, 256, 0, stream>>>(X, Wq, Wk, Wv, QKVb);
    attn_mfma<<<384, 256, 0, stream>>>(QKVb, Attnb);
    gemm_out<<<192, 256, 0, stream>>>(Attnb, Wo, out);
}

// Round 6
// 47.646 us; speedup vs baseline: 3.3846x; 1.9183x over previous
//
#include <hip/hip_runtime.h>
#include <stdint.h>

// ---- problem constants ----
#define S_LEN   2048
#define HIDDEN  768
#define NHEADS  12
#define QKV_LD  2304   // fused q|k|v row stride (elements)
#define NW      589824 // 768*768

typedef __attribute__((ext_vector_type(8))) short short8;
typedef __attribute__((ext_vector_type(4))) float f32x4;

typedef const __attribute__((address_space(1))) void* gas_ptr;
typedef __attribute__((address_space(3))) void* las_ptr;

__device__ __forceinline__ short f2b(float f) {
    union { float f; uint32_t u; } v; v.f = f;
    uint32_t u = v.u;
    uint32_t r = (u + 0x7FFFu + ((u >> 16) & 1u)) >> 16;
    return (short)r;
}

// ---------------- all f32 -> bf16 converts in one launch ----------------
// blocks [0,1536): X. blocks [1536, 1536+4*576): Wq,Wk,Wv,Wo.
__global__ __launch_bounds__(256)
void convert_all(const float* __restrict__ X,
                 const float* __restrict__ Wq, const float* __restrict__ Wk,
                 const float* __restrict__ Wv, const float* __restrict__ Wo,
                 short* __restrict__ Xb, short* __restrict__ Wqkvb,
                 short* __restrict__ Wob) {
    int b = blockIdx.x;
    const float* src;
    short* dst;
    int i;
    if (b < 1536) {
        src = X; dst = Xb; i = b * 1024 + threadIdx.x * 4;
    } else {
        int wb = (b - 1536) / 576, lb = (b - 1536) % 576;
        src = wb == 0 ? Wq : wb == 1 ? Wk : wb == 2 ? Wv : Wo;
        dst = wb < 3 ? Wqkvb + wb * NW : Wob;
        i = lb * 1024 + threadIdx.x * 4;
    }
    float4 v = *(const float4*)(src + i);
    *(short4*)(dst + i) = make_short4(f2b(v.x), f2b(v.y), f2b(v.z), f2b(v.w));
}

// ========== bf16 GEMM, 64x128 tile, BK=64, dbuf, global_load_lds ==========
// C[m][n] = sum_k A[m][k] * B[n][k].  A: Mx768 bf16, B: Nx768 bf16 (B^T input).
// 4 waves in 2x2 grid; wave covers 32 rows x 64 cols. XOR-swizzled LDS.
template<int OUT_BF16>
__device__ __forceinline__ void gemm64x128(const short* __restrict__ A,
    const short* __restrict__ B, void* __restrict__ Cv,
    int bm, int bn, int ldc) {
    __shared__ short sA[2][64 * 64];     // 8KB per buf
    __shared__ short sB[2][128 * 64];    // 16KB per buf  (total 48KB)

    const int tid = threadIdx.x, lane = tid & 63, w = tid >> 6;
    const int wr = w >> 1, wc = w & 1;

    f32x4 acc[2][4] = {};

    auto stage = [&](int buf, int k0) {
        #pragma unroll
        for (int c = 0; c < 2; ++c) {
            int r = w * 16 + c * 8 + (lane >> 3);
            int scb = ((lane & 7) * 16) ^ ((r & 7) << 4);
            const char* gp = (const char*)(A + (size_t)(bm * 64 + r) * 768 + k0) + scb;
            __builtin_amdgcn_global_load_lds((gas_ptr)gp,
                (las_ptr)((char*)&sA[buf][0] + w * 2048 + c * 1024), 16, 0, 0);
        }
        #pragma unroll
        for (int c = 0; c < 4; ++c) {
            int r = w * 32 + c * 8 + (lane >> 3);
            int scb = ((lane & 7) * 16) ^ ((r & 7) << 4);
            const char* gp = (const char*)(B + (size_t)(bn * 128 + r) * 768 + k0) + scb;
            __builtin_amdgcn_global_load_lds((gas_ptr)gp,
                (las_ptr)((char*)&sB[buf][0] + w * 4096 + c * 1024), 16, 0, 0);
        }
    };

    stage(0, 0);
    __syncthreads();
    int cur = 0;
    for (int t = 0; t < 12; ++t) {
        if (t < 11) stage(cur ^ 1, (t + 1) * 64);
        #pragma unroll
        for (int kh = 0; kh < 2; ++kh) {
            const int kb = kh * 64 + ((lane >> 4) << 4);
            short8 av[2], bv[4];
            #pragma unroll
            for (int mi = 0; mi < 2; ++mi) {
                int row = wr * 32 + mi * 16 + (lane & 15);
                av[mi] = *(const short8*)((const char*)&sA[cur][0] + row * 128 + (kb ^ ((row & 7) << 4)));
            }
            #pragma unroll
            for (int ni = 0; ni < 4; ++ni) {
                int row = wc * 64 + ni * 16 + (lane & 15);
                bv[ni] = *(const short8*)((const char*)&sB[cur][0] + row * 128 + (kb ^ ((row & 7) << 4)));
            }
            #pragma unroll
            for (int mi = 0; mi < 2; ++mi)
                #pragma unroll
                for (int ni = 0; ni < 4; ++ni)
                    acc[mi][ni] = __builtin_amdgcn_mfma_f32_16x16x32_bf16(
                        av[mi], bv[ni], acc[mi][ni], 0, 0, 0);
        }
        __syncthreads();
        cur ^= 1;
    }

    const int crow0 = bm * 64 + wr * 32;
    const int ccol0 = bn * 128 + wc * 64;
    #pragma unroll
    for (int mi = 0; mi < 2; ++mi)
        #pragma unroll
        for (int ni = 0; ni < 4; ++ni)
            #pragma unroll
            for (int r = 0; r < 4; ++r) {
                int grow = crow0 + mi * 16 + ((lane >> 4) << 2) + r;
                int gcol = ccol0 + ni * 16 + (lane & 15);
                if (OUT_BF16)
                    ((short*)Cv)[(size_t)grow * ldc + gcol] = f2b(acc[mi][ni][r]);
                else
                    ((float*)Cv)[(size_t)grow * ldc + gcol] = acc[mi][ni][r];
            }
}

// Kernel 1: QKV = Xb @ Wqkvb^T. M=2048,N=2304 -> 32x18 = 576 blocks (8*72).
__global__ __launch_bounds__(256)
void gemm_qkv(const short* __restrict__ Xb, const short* __restrict__ Wqkvb,
              short* __restrict__ C) {
    const int bid = blockIdx.x;
    const int sw = (bid & 7) * 72 + (bid >> 3);   // bijective XCD chunking
    gemm64x128<1>(Xb, Wqkvb, C, sw / 18, sw % 18, QKV_LD);
}

// Kernel 3: out = Attnb @ Wob^T. M=2048,N=768 -> 32x6 = 192 blocks (8*24).
__global__ __launch_bounds__(256)
void gemm_out(const short* __restrict__ A, const short* __restrict__ Wob,
              float* __restrict__ C) {
    const int bid = blockIdx.x;
    const int sw = (bid & 7) * 24 + (bid >> 3);
    gemm64x128<0>(A, Wob, C, sw / 6, sw % 6, HIDDEN);
}

// ================= Kernel 2: MFMA sliding-window attention ===================
// QKV: [S][2304] bf16. O: [S][768] bf16. Block = (head, 64-query tile).
__global__ __launch_bounds__(256)
void attn_mfma(const short* __restrict__ QKV, short* __restrict__ O) {
    __shared__ short sK[128 * 64];       // [kt][d]  swz, 16KB
    __shared__ short sVt[64 * 128];      // [d][kt]  swz, 16KB
    __shared__ short sP[4][16 * 128];    // per-wave [q][kt] swz, 16KB

    const int bid = blockIdx.x;                 // 384 = 8*48
    const int task = (bid & 7) * 48 + (bid >> 3);
    const int h = task % NHEADS;
    const int s0 = (task / NHEADS) * 64;
    const int tid = threadIdx.x, lane = tid & 63, w = tid >> 6;

    #pragma unroll
    for (int c = 0; c < 4; ++c) {
        int r = (w * 4 + c) * 8 + (lane >> 3);
        int gr = s0 - 64 + r; if (gr < 0) gr = 0;
        int scb = ((lane & 7) * 16) ^ ((r & 7) << 4);
        const char* gp = (const char*)(QKV + (size_t)gr * QKV_LD + 768 + h * 64) + scb;
        __builtin_amdgcn_global_load_lds((gas_ptr)gp,
            (las_ptr)((char*)sK + (w * 4 + c) * 1024), 16, 0, 0);
    }
    {   // V transposed: thread = (4 keys, 8 dims) -> 8x ds_write_b64
        const int d0 = (tid & 7) * 8;
        const int kbase = (tid >> 3) * 4;
        short8 v[4];
        #pragma unroll
        for (int i = 0; i < 4; ++i) {
            int gr = s0 - 64 + kbase + i; if (gr < 0) gr = 0;
            v[i] = *(const short8*)(QKV + (size_t)gr * QKV_LD + 1536 + h * 64 + d0);
        }
        #pragma unroll
        for (int j = 0; j < 8; ++j) {
            int row = d0 + j;
            int b = row * 256 + ((kbase * 2) ^ ((row & 7) << 4));
            *(short4*)((char*)sVt + b) = make_short4(v[0][j], v[1][j], v[2][j], v[3][j]);
        }
    }
    const int qrow = w * 16 + (lane & 15);
    short8 qf[2];
    #pragma unroll
    for (int kk = 0; kk < 2; ++kk)
        qf[kk] = *(const short8*)(QKV + (size_t)(s0 + qrow) * QKV_LD + h * 64
                                  + kk * 32 + ((lane >> 4) << 3));
    __syncthreads();

    f32x4 s_acc[8];
    #pragma unroll
    for (int ct = 0; ct < 8; ++ct) {
        s_acc[ct] = (f32x4){0.f, 0.f, 0.f, 0.f};
        int krow = ct * 16 + (lane & 15);
        #pragma unroll
        for (int kk = 0; kk < 2; ++kk) {
            int cb = kk * 64 + ((lane >> 4) << 4);
            short8 kf = *(const short8*)((const char*)sK + krow * 128 + (cb ^ ((krow & 7) << 4)));
            s_acc[ct] = __builtin_amdgcn_mfma_f32_16x16x32_bf16(qf[kk], kf, s_acc[ct], 0, 0, 0);
        }
    }

    const int kcol = lane & 15;
    const int qb = w * 16 + ((lane >> 4) << 2);
    float p[8][4];
    #pragma unroll
    for (int r = 0; r < 4; ++r) {
        int q = qb + r;
        float m = -1e30f;
        #pragma unroll
        for (int ct = 0; ct < 8; ++ct) {
            int kt = ct * 16 + kcol;
            bool valid = (kt > q) && (kt <= q + 64) && (s0 + kt >= 64);
            float sc = valid ? s_acc[ct][r] * 0.125f : -1e30f;
            p[ct][r] = sc;
            m = fmaxf(m, sc);
        }
        #pragma unroll
        for (int off = 1; off < 16; off <<= 1) m = fmaxf(m, __shfl_xor(m, off));
        float sm = 0.f;
        #pragma unroll
        for (int ct = 0; ct < 8; ++ct) {
            float e = __expf(p[ct][r] - m);
            p[ct][r] = e;
            sm += e;
        }
        #pragma unroll
        for (int off = 1; off < 16; off <<= 1) sm += __shfl_xor(sm, off);
        float inv = 1.f / sm;
        #pragma unroll
        for (int ct = 0; ct < 8; ++ct) p[ct][r] *= inv;
    }

    #pragma unroll
    for (int ct = 0; ct < 8; ++ct)
        #pragma unroll
        for (int r = 0; r < 4; ++r) {
            int row = ((lane >> 4) << 2) + r;
            int b = row * 256 + (((ct * 16 + kcol) * 2) ^ ((row & 7) << 4));
            *(short*)((char*)&sP[w][0] + b) = f2b(p[ct][r]);
        }

    short8 pf[4];
    #pragma unroll
    for (int kk = 0; kk < 4; ++kk) {
        int row = lane & 15;
        int cb = kk * 64 + ((lane >> 4) << 4);
        pf[kk] = *(const short8*)((const char*)&sP[w][0] + row * 256 + (cb ^ ((row & 7) << 4)));
    }
    f32x4 o_acc[4];
    #pragma unroll
    for (int nt = 0; nt < 4; ++nt) {
        o_acc[nt] = (f32x4){0.f, 0.f, 0.f, 0.f};
        #pragma unroll
        for (int kk = 0; kk < 4; ++kk) {
            int vrow = nt * 16 + (lane & 15);
            int cb = kk * 64 + ((lane >> 4) << 4);
            short8 vf = *(const short8*)((const char*)sVt + vrow * 256 + (cb ^ ((vrow & 7) << 4)));
            o_acc[nt] = __builtin_amdgcn_mfma_f32_16x16x32_bf16(pf[kk], vf, o_acc[nt], 0, 0, 0);
        }
    }

    #pragma unroll
    for (int nt = 0; nt < 4; ++nt)
        #pragma unroll
        for (int r = 0; r < 4; ++r) {
            int q = s0 + qb + r;
            int dcol = h * 64 + nt * 16 + (lane & 15);
            O[(size_t)q * HIDDEN + dcol] = f2b(o_acc[nt][r]);
        }
}

// ---------------- launcher ----------------
extern "C" void kernel_launch(void* const* d_in, const int* in_sizes, int n_in,
                              void* d_out, int out_size, void* d_ws, size_t ws_size,
                              hipStream_t stream) {
    const float* X  = (const float*)d_in[0];
    const float* Wq = (const float*)d_in[1];
    const float* Wk = (const float*)d_in[2];
    const float* Wv = (const float*)d_in[3];
    const float* Wo = (const float*)d_in[4];
    float* out = (float*)d_out;

    char* ws = (char*)d_ws;
    short* Xb    = (short*)ws;                   // 2048*768   bf16
    short* Wqkvb = (short*)(ws + 3145728);       // 2304*768   bf16
    short* Wob   = (short*)(ws + 6684672);       // 768*768    bf16
    short* QKVb  = (short*)(ws + 7864320);       // 2048*2304  bf16
    short* Attnb = (short*)(ws + 17301504);      // 2048*768   bf16

    convert_all<<<1536 + 4 * 576, 256, 0, stream>>>(X, Wq, Wk, Wv, Wo, Xb, Wqkvb, Wob);
    gemm_qkv<<<576, 256, 0, stream>>>(Xb, Wqkvb, QKVb);
    attn_mfma<<<384, 256, 0, stream>>>(QKVb, Attnb);
    gemm_out<<<192, 256, 0, stream>>>(Attnb, Wob, out);
}